// Round 6
// baseline (1314.940 us; speedup 1.0000x reference)
//
#include <hip/hip_runtime.h>
#include <cstdint>

// ---------------- problem constants ----------------
#define NYD   256
#define NXD   256
#define PADC  22            // PML + FD_PAD
#define NYP_  300           // NY + 2*PAD
#define NXP_  300
#define NTT   250
#define NSHOT_ 2
#define NSRC_  8
#define NREC_  64
#define DT_   0.0005f

// guarded-array geometry
#define GDN   28
#define STP   356           // NXP_ + 2*GDN (multiple of 4 -> float4 rows stay aligned)
#define FP    (STP*STP)     // per-shot field words (126736)

// tile geometry: 8x32 output tile, 2 steps per launch
#define BY    8
#define BX    32
#define NTX   10            // ceil(300/32)
#define NTY   38            // ceil(300/8)
#define TPS   380           // tiles per shot
#define NWG   760           // = 8 XCDs * 95 -> perfect bijective swizzle

// ---------------- zero workspace ----------------
__global__ void zero_kernel(float* __restrict__ p, long n) {
    long i = (long)blockIdx.x * blockDim.x + threadIdx.x;
    long stride = (long)gridDim.x * blockDim.x;
    for (; i < n; i += stride) p[i] = 0.0f;
}

// ---------------- setup: v2dt2, PML profiles, receiver tile bins ----------------
__global__ void populate_kernel(const float* __restrict__ v,
                                const int* __restrict__ recloc,
                                float* __restrict__ v2dt2,   // [FP], guard stays 0
                                float* __restrict__ prof,    // [2*STP]: a, b (guard 0)
                                unsigned long long* __restrict__ recbin) { // [2][TPS]
    int i = blockIdx.x * 256 + threadIdx.x;

    if (i < NYP_ * NXP_) {
        int y = i / NXP_, x = i % NXP_;
        int vy = min(max(y - PADC, 0), NYD - 1);
        int vx = min(max(x - PADC, 0), NXD - 1);
        float vv = v[vy * NXD + vx];
        v2dt2[(y + GDN) * STP + (x + GDN)] = vv * vv * (DT_ * DT_);
    }

    if (i < NYP_) {  // DY == DX and NYP == NXP: one profile pair serves both axes
        float fi = (float)i;
        float d = fmaxf(22.0f - fi, fi - 277.0f);
        float frac = fminf(fmaxf(d * (1.0f / 20.0f), 0.0f), 1.0f);
        float sigma_max = 3.0f * 4000.0f * logf(1000.0f) / (2.0f * 20.0f * 5.0f);
        float sigma = sigma_max * frac * frac;
        float alpha = 3.14159265358979323846f * 25.0f * (1.0f - frac);
        float b = expf(-(sigma + alpha) * DT_);
        float a = sigma / (sigma + alpha + 1e-9f) * (b - 1.0f);
        prof[GDN + i] = a;
        prof[STP + GDN + i] = b;
    }

    if (i < NSHOT_ * NREC_) {
        int ry = recloc[2 * i] + PADC;
        int rx = recloc[2 * i + 1] + PADC;
        int shot = i / NREC_;
        int tl = (ry / BY) * NTX + (rx / BX);
        atomicOr(&recbin[shot * TPS + tl], 1ull << (i % NREC_));
    }
}

// ---------------- fused kernel: 2 time steps per launch ----------------
// Regions (O = 8x32 output tile at (ty0,tx0)):
//   swf0 = wf(t)   on [ty0-8,+16) x [tx0-8,+40)   (24x48)
//   spy  = psiy    on [ty0-6,+14) x [tx0-4,+36)   (20x40), updated in place t->t+1,
//          then rows 4..15 x cols 4..35 updated t+1->t+2
//   spx  = psix    on [ty0-4,+12) x [tx0-8,+40)   (16x48), cols 2..45 updated t->t+1,
//          then rows 4..11 x cols 6..41 updated t+1->t+2
//   W1   = O+4 ring: [ty0-4,+12) x [tx0-4,+36)    (16x40): swf1, szy, szx, sv2, swm
// Phases (barrier-separated, all intermediates in LDS):
//   stage(float4) -> psi(t+1) -> wf(t+1)+zeta(t+1) [src amps[t] over all W1]
//   -> psi(t+2) on O+2 -> wf(t+2)+zeta(t+2)+writeback on O [src amps[t+1]].
// Guard ring (wf/psi/zeta/v2/prof all 0 there) keeps Dirichlet boundaries exact
// for every staged access; zeta ping-pongs (neighbors read zeta(t) where we
// write zeta(t+2)). Arithmetic per step is expression-identical to the
// verified single-step kernel.
__global__ __launch_bounds__(256) void fused2_kernel(
    const float* __restrict__ wfm_g,   // wf(t-1)
    const float* __restrict__ wfc_g,   // wf(t)
    float* __restrict__ w1_g,          // out: wf(t+1)
    float* __restrict__ w2_g,          // out: wf(t+2)
    const float* __restrict__ pyr_g, float* __restrict__ pyw_g,
    const float* __restrict__ pxr_g, float* __restrict__ pxw_g,
    const float* __restrict__ zyr_g, float* __restrict__ zyw_g,
    const float* __restrict__ zxr_g, float* __restrict__ zxw_g,
    const float* __restrict__ v2_g, const float* __restrict__ prof,
    const unsigned long long* __restrict__ recbin,
    const int* __restrict__ srcloc, const int* __restrict__ recloc,
    const float* __restrict__ amps,   // [NSHOT][NSRC][NT]
    float* __restrict__ out,          // [NSHOT][NREC][NT]
    int t) {
    // bijective XCD swizzle: NWG = 760 = 8 * 95
    const int orig = blockIdx.x;
    const int wgid = (orig & 7) * 95 + (orig >> 3);
    const int shot = wgid / TPS;
    const int tl   = wgid - shot * TPS;
    const int ty0  = (tl / NTX) * BY;
    const int tx0  = (tl % NTX) * BX;

    const float* wfm = wfm_g + shot * FP;
    const float* wfc = wfc_g + shot * FP;
    float*       w1o = w1_g  + shot * FP;
    float*       w2o = w2_g  + shot * FP;
    const float* pyr = pyr_g + shot * FP;
    float*       pyw = pyw_g + shot * FP;
    const float* pxr = pxr_g + shot * FP;
    float*       pxw = pxw_g + shot * FP;
    const float* zyr = zyr_g + shot * FP;
    float*       zyw = zyw_g + shot * FP;
    const float* zxr = zxr_g + shot * FP;
    float*       zxw = zxw_g + shot * FP;

    __shared__ float swf0[24][48];
    __shared__ float spy [20][40];
    __shared__ float spx [16][48];
    __shared__ float swf1[16][40];
    __shared__ float szy [16][40];
    __shared__ float szx [16][40];
    __shared__ float sv2 [16][40];
    __shared__ float swm [16][40];
    __shared__ float sya[24], syb[24], sxa[48], sxb[48];
    __shared__ int   ssy[NSRC_], ssx[NSRC_], sry[NREC_], srx[NREC_];
    __shared__ unsigned long long srb;

    const int tid = threadIdx.x;

    // ---- stage (1320 float4, all independent) ----
#pragma unroll
    for (int li = 0; li < 6; li++) {
        int lin = tid + li * 256;
        if (lin < 288) {                     // swf0: 24 x 12 f4 from (ty0-8, tx0-8)
            int rr = lin / 12, cc = lin % 12;
            *reinterpret_cast<float4*>(&swf0[rr][cc * 4]) =
                *reinterpret_cast<const float4*>(wfc + (ty0 - 8 + rr + GDN) * STP + (tx0 - 8 + GDN) + cc * 4);
        } else if (lin < 488) {              // spy: 20 x 10 f4 from (ty0-6, tx0-4)
            int l = lin - 288; int rr = l / 10, cc = l % 10;
            *reinterpret_cast<float4*>(&spy[rr][cc * 4]) =
                *reinterpret_cast<const float4*>(pyr + (ty0 - 6 + rr + GDN) * STP + (tx0 - 4 + GDN) + cc * 4);
        } else if (lin < 680) {              // spx: 16 x 12 f4 from (ty0-4, tx0-8)
            int l = lin - 488; int rr = l / 12, cc = l % 12;
            *reinterpret_cast<float4*>(&spx[rr][cc * 4]) =
                *reinterpret_cast<const float4*>(pxr + (ty0 - 4 + rr + GDN) * STP + (tx0 - 8 + GDN) + cc * 4);
        } else if (lin < 840) {              // szy: 16 x 10 f4 from (ty0-4, tx0-4)
            int l = lin - 680; int rr = l / 10, cc = l % 10;
            *reinterpret_cast<float4*>(&szy[rr][cc * 4]) =
                *reinterpret_cast<const float4*>(zyr + (ty0 - 4 + rr + GDN) * STP + (tx0 - 4 + GDN) + cc * 4);
        } else if (lin < 1000) {             // szx
            int l = lin - 840; int rr = l / 10, cc = l % 10;
            *reinterpret_cast<float4*>(&szx[rr][cc * 4]) =
                *reinterpret_cast<const float4*>(zxr + (ty0 - 4 + rr + GDN) * STP + (tx0 - 4 + GDN) + cc * 4);
        } else if (lin < 1160) {             // sv2
            int l = lin - 1000; int rr = l / 10, cc = l % 10;
            *reinterpret_cast<float4*>(&sv2[rr][cc * 4]) =
                *reinterpret_cast<const float4*>(v2_g + (ty0 - 4 + rr + GDN) * STP + (tx0 - 4 + GDN) + cc * 4);
        } else if (lin < 1320) {             // swm = wf(t-1) on W1
            int l = lin - 1160; int rr = l / 10, cc = l % 10;
            *reinterpret_cast<float4*>(&swm[rr][cc * 4]) =
                *reinterpret_cast<const float4*>(wfm + (ty0 - 4 + rr + GDN) * STP + (tx0 - 4 + GDN) + cc * 4);
        }
    }
    if (tid < 24) {
        sya[tid] = prof[GDN + ty0 - 8 + tid];
        syb[tid] = prof[STP + GDN + ty0 - 8 + tid];
    }
    if (tid < 48) {
        sxa[tid] = prof[GDN + tx0 - 8 + tid];
        sxb[tid] = prof[STP + GDN + tx0 - 8 + tid];
    }
    if (tid < NSRC_) {
        ssy[tid] = srcloc[(shot * NSRC_ + tid) * 2]     + PADC;
        ssx[tid] = srcloc[(shot * NSRC_ + tid) * 2 + 1] + PADC;
    }
    if (tid < NREC_) {
        sry[tid] = recloc[(shot * NREC_ + tid) * 2]     + PADC;
        srx[tid] = recloc[(shot * NREC_ + tid) * 2 + 1] + PADC;
    }
    if (tid == 0) srb = recbin[shot * TPS + tl];
    __syncthreads();

    const float ih  = 0.2f;    // 1/DY
    const float ih2 = 0.04f;   // 1/DY^2
    const float C1A = 2.0f / 3.0f, C1B = 1.0f / 12.0f;
    const float C2A = 4.0f / 3.0f, C2B = -1.0f / 12.0f, C2C = -2.5f;

    // ---- psi(t) -> psi(t+1), in place (800 + 704 cells) ----
#pragma unroll
    for (int li = 0; li < 6; li++) {
        int lin = tid + li * 256;
        if (lin < 800) {                       // spy cell (r,c): y=ty0-6+r, x=tx0-4+c
            int r = lin / 40, c = lin % 40;
            float dw = (C1A * (swf0[r + 3][c + 4] - swf0[r + 1][c + 4])
                      - C1B * (swf0[r + 4][c + 4] - swf0[r][c + 4])) * ih;
            spy[r][c] = syb[r + 2] * spy[r][c] + sya[r + 2] * dw;
        } else if (lin < 1504) {               // spx cols 2..45: y=ty0-4+r, x=tx0-8+c
            int l = lin - 800; int r = l / 44, c = l % 44 + 2;
            float dw = (C1A * (swf0[r + 4][c + 1] - swf0[r + 4][c - 1])
                      - C1B * (swf0[r + 4][c + 2] - swf0[r + 4][c - 2])) * ih;
            spx[r][c] = sxb[c] * spx[r][c] + sxa[c] * dw;
        }
    }
    __syncthreads();

    // ---- wf(t+1) + zeta(t+1) on W1 (640 cells) ----
#pragma unroll
    for (int li = 0; li < 3; li++) {
        int lin = tid + li * 256;
        if (lin < 640) {
            int r = lin / 40, c = lin % 40;    // y=ty0-4+r, x=tx0-4+c
            float wc = swf0[r + 4][c + 4];
            float d2y = (C2B * (swf0[r + 2][c + 4] + swf0[r + 6][c + 4])
                       + C2A * (swf0[r + 3][c + 4] + swf0[r + 5][c + 4]) + C2C * wc) * ih2;
            float d2x = (C2B * (swf0[r + 4][c + 2] + swf0[r + 4][c + 6])
                       + C2A * (swf0[r + 4][c + 3] + swf0[r + 4][c + 5]) + C2C * wc) * ih2;
            float dpy = (C1A * (spy[r + 3][c] - spy[r + 1][c])
                       - C1B * (spy[r + 4][c] - spy[r][c])) * ih;
            float dpx = (C1A * (spx[r][c + 5] - spx[r][c + 3])
                       - C1B * (spx[r][c + 6] - spx[r][c + 2])) * ih;
            float zy1 = syb[r + 4] * szy[r][c] + sya[r + 4] * (d2y + dpy);
            float zx1 = sxb[c + 4] * szx[r][c] + sxa[c + 4] * (d2x + dpx);
            szy[r][c] = zy1;
            szx[r][c] = zx1;
            float vd = sv2[r][c];
            float w1 = 2.0f * wc - swm[r][c] + vd * (d2y + d2x + dpy + dpx + zy1 + zx1);
            int y = ty0 - 4 + r, x = tx0 - 4 + c;
#pragma unroll
            for (int q = 0; q < NSRC_; q++)
                if (ssy[q] == y && ssx[q] == x)
                    w1 += vd * amps[(shot * NSRC_ + q) * NTT + t];
            swf1[r][c] = w1;
        }
    }
    __syncthreads();

    // ---- psi(t+1) -> psi(t+2) on O+2 (384 + 288 cells), in place ----
#pragma unroll
    for (int li = 0; li < 3; li++) {
        int lin = tid + li * 256;
        if (lin < 384) {                       // psiy(t+2): y=ty0-2+r, x=tx0+c
            int r = lin / 32, c = lin % 32;
            float dw1 = (C1A * (swf1[r + 3][c + 4] - swf1[r + 1][c + 4])
                       - C1B * (swf1[r + 4][c + 4] - swf1[r][c + 4])) * ih;
            spy[r + 4][c + 4] = syb[r + 6] * spy[r + 4][c + 4] + sya[r + 6] * dw1;
        } else if (lin < 672) {                // psix(t+2): y=ty0+r, x=tx0-2+c2
            int l = lin - 384; int r = l / 36, c2 = l % 36;
            float dw1 = (C1A * (swf1[r + 4][c2 + 3] - swf1[r + 4][c2 + 1])
                       - C1B * (swf1[r + 4][c2 + 4] - swf1[r + 4][c2])) * ih;
            spx[r + 4][c2 + 6] = sxb[c2 + 6] * spx[r + 4][c2 + 6] + sxa[c2 + 6] * dw1;
        }
    }
    __syncthreads();

    // ---- wf(t+2) + zeta(t+2) + writeback on O (1 cell/thread) ----
    {
        int ly = tid >> 5, lx = tid & 31;
        int y = ty0 + ly, x = tx0 + lx;
        float w1c = swf1[ly + 4][lx + 4];
        float d2y1 = (C2B * (swf1[ly + 2][lx + 4] + swf1[ly + 6][lx + 4])
                    + C2A * (swf1[ly + 3][lx + 4] + swf1[ly + 5][lx + 4]) + C2C * w1c) * ih2;
        float d2x1 = (C2B * (swf1[ly + 4][lx + 2] + swf1[ly + 4][lx + 6])
                    + C2A * (swf1[ly + 4][lx + 3] + swf1[ly + 4][lx + 5]) + C2C * w1c) * ih2;
        float dpy2 = (C1A * (spy[ly + 7][lx + 4] - spy[ly + 5][lx + 4])
                    - C1B * (spy[ly + 8][lx + 4] - spy[ly + 4][lx + 4])) * ih;
        float dpx2 = (C1A * (spx[ly + 4][lx + 9] - spx[ly + 4][lx + 7])
                    - C1B * (spx[ly + 4][lx + 10] - spx[ly + 4][lx + 6])) * ih;
        float zy2 = syb[ly + 8] * szy[ly + 4][lx + 4] + sya[ly + 8] * (d2y1 + dpy2);
        float zx2 = sxb[lx + 8] * szx[ly + 4][lx + 4] + sxa[lx + 8] * (d2x1 + dpx2);
        float vd = sv2[ly + 4][lx + 4];
        float w2 = 2.0f * w1c - swf0[ly + 8][lx + 8]
                 + vd * (d2y1 + d2x1 + dpy2 + dpx2 + zy2 + zx2);
#pragma unroll
        for (int q = 0; q < NSRC_; q++)
            if (ssy[q] == y && ssx[q] == x)
                w2 += vd * amps[(shot * NSRC_ + q) * NTT + t + 1];

        if (y < NYP_ && x < NXP_) {
            int g = (y + GDN) * STP + (x + GDN);
            w1o[g] = w1c;
            w2o[g] = w2;
            pyw[g] = spy[ly + 6][lx + 4];
            pxw[g] = spx[ly + 4][lx + 8];
            zyw[g] = zy2;
            zxw[g] = zx2;
            unsigned long long rb = srb;
            while (rb) {
                int r = __ffsll(rb) - 1;
                rb &= rb - 1;
                if (sry[r] == y && srx[r] == x) {
                    out[(shot * NREC_ + r) * NTT + t]     = w1c;
                    out[(shot * NREC_ + r) * NTT + t + 1] = w2;
                }
            }
        }
    }
}

// ---------------- host ----------------
extern "C" void kernel_launch(void* const* d_in, const int* in_sizes, int n_in,
                              void* d_out, int out_size, void* d_ws, size_t ws_size,
                              hipStream_t stream) {
    const float* v      = (const float*)d_in[0];
    const float* amps   = (const float*)d_in[1];
    const int*   srcloc = (const int*)d_in[2];
    const int*   recloc = (const int*)d_in[3];
    float* out = (float*)d_out;

    float* base = (float*)d_ws;
    float* W0  = base;             // each: [2 shots][FP]
    float* W1  = W0  + 2L * FP;
    float* W2  = W1  + 2L * FP;
    float* W3  = W2  + 2L * FP;
    float* PY0 = W3  + 2L * FP;
    float* PY1 = PY0 + 2L * FP;
    float* PX0 = PY1 + 2L * FP;
    float* PX1 = PX0 + 2L * FP;
    float* ZY0 = PX1 + 2L * FP;
    float* ZY1 = ZY0 + 2L * FP;
    float* ZX0 = ZY1 + 2L * FP;
    float* ZX1 = ZX0 + 2L * FP;
    float* V2  = ZX1 + 2L * FP;    // [FP], shot-independent
    float* PROF = V2 + FP;         // [2*STP]
    unsigned long long* RECBIN = (unsigned long long*)(PROF + 2 * STP);  // [2][TPS]

    const long total_words = 25L * FP + 2 * STP + 2L * NSHOT_ * TPS;

    zero_kernel<<<2048, 256, 0, stream>>>(base, total_words);
    populate_kernel<<<(NYP_ * NXP_ + 255) / 256, 256, 0, stream>>>(
        v, recloc, V2, PROF, RECBIN);

    // 125 launches of 2 fused steps; wf buffers rotate (A,B,C,D)->(C,D,A,B)
    for (int k = 0; k < NTT / 2; k++) {
        const bool o = (k & 1);
        fused2_kernel<<<NWG, 256, 0, stream>>>(
            o ? W2 : W0, o ? W3 : W1,   // wf(t-1), wf(t)
            o ? W0 : W2, o ? W1 : W3,   // wf(t+1), wf(t+2)
            o ? PY1 : PY0, o ? PY0 : PY1,
            o ? PX1 : PX0, o ? PX0 : PX1,
            o ? ZY1 : ZY0, o ? ZY0 : ZY1,
            o ? ZX1 : ZX0, o ? ZX0 : ZX1,
            V2, PROF, RECBIN, srcloc, recloc, amps, out, 2 * k);
    }
}